// Round 1
// baseline (3686.991 us; speedup 1.0000x reference)
//
#include <hip/hip_runtime.h>

static inline int idiv_up(int a, int b) { return (a + b - 1) / b; }

// ---------------- degree / dinv ----------------

__global__ __launch_bounds__(256) void count_deg_kernel(
    const int* __restrict__ colL, const int* __restrict__ colN,
    int eL, int eN,
    float* __restrict__ degL, float* __restrict__ degN)
{
    int i = blockIdx.x * 256 + threadIdx.x;
    if (i < eL) atomicAdd(&degL[colL[i]], 1.0f);
    if (i < eN) atomicAdd(&degN[colN[i]], 1.0f);
}

__global__ __launch_bounds__(256) void dinv_kernel(
    float* __restrict__ degL, float* __restrict__ degN, int n)
{
    int i = blockIdx.x * 256 + threadIdx.x;
    if (i < n) {
        degL[i] = rsqrtf(degL[i] + 1.0f);   // +1 self loop
        degN[i] = rsqrtf(degN[i] + 1.0f);
    }
}

// ---------------- GEMM: y = acc = (A @ W) * dinv[row]  ----------------
// A is [n][128]; optional BN(scale,shift)+ReLU applied to A on load.
// blockIdx.y selects the (W, dinv, y, acc) set: 0 = low, 1 = nd.

template<int NC>
__global__ __launch_bounds__(256) void gemm_kernel(
    const float* __restrict__ A, int n,
    const float* __restrict__ Wa, const float* __restrict__ Wb,
    const float* __restrict__ dinva, const float* __restrict__ dinvb,
    float* __restrict__ ya, float* __restrict__ yb,
    float* __restrict__ acca, float* __restrict__ accb,
    const float* __restrict__ bn_scale, const float* __restrict__ bn_shift)
{
    constexpr int K   = 128;
    constexpr int TR  = 64;        // rows per block
    constexpr int CG  = NC / 4;    // float4 column groups
    constexpr int TY  = 256 / CG;  // thread-row groups
    constexpr int RPT = TR / TY;   // rows per thread

    __shared__ float xs[TR][K];

    const float* W    = blockIdx.y ? Wb    : Wa;
    const float* dinv = blockIdx.y ? dinvb : dinva;
    float* y          = blockIdx.y ? yb    : ya;
    float* acc        = blockIdx.y ? accb  : acca;

    const int row0 = blockIdx.x * TR;
    const int t = threadIdx.x;

    const float4* A4 = (const float4*)A;
    #pragma unroll
    for (int i = 0; i < (TR * (K / 4)) / 256; ++i) {
        int fl = i * 256 + t;
        int r  = fl >> 5;       // K/4 == 32
        int c4 = fl & 31;
        float4 v = make_float4(0.f, 0.f, 0.f, 0.f);
        int rr = row0 + r;
        if (rr < n) v = A4[(size_t)rr * 32 + c4];
        if (bn_scale) {
            float4 sc = ((const float4*)bn_scale)[c4];
            float4 sh = ((const float4*)bn_shift)[c4];
            v.x = fmaxf(v.x * sc.x + sh.x, 0.f);
            v.y = fmaxf(v.y * sc.y + sh.y, 0.f);
            v.z = fmaxf(v.z * sc.z + sh.z, 0.f);
            v.w = fmaxf(v.w * sc.w + sh.w, 0.f);
        }
        *(float4*)&xs[r][c4 * 4] = v;
    }
    __syncthreads();

    const int cg = t % CG;
    const int ty = t / CG;

    float4 accv[RPT];
    #pragma unroll
    for (int r = 0; r < RPT; ++r) accv[r] = make_float4(0.f, 0.f, 0.f, 0.f);

    const float4* W4 = (const float4*)W;
    for (int k = 0; k < K; k += 4) {
        float4 w0 = W4[(size_t)(k + 0) * CG + cg];
        float4 w1 = W4[(size_t)(k + 1) * CG + cg];
        float4 w2 = W4[(size_t)(k + 2) * CG + cg];
        float4 w3 = W4[(size_t)(k + 3) * CG + cg];
        #pragma unroll
        for (int r = 0; r < RPT; ++r) {
            float4 a = *(const float4*)&xs[ty * RPT + r][k];
            accv[r].x += a.x * w0.x; accv[r].y += a.x * w0.y; accv[r].z += a.x * w0.z; accv[r].w += a.x * w0.w;
            accv[r].x += a.y * w1.x; accv[r].y += a.y * w1.y; accv[r].z += a.y * w1.z; accv[r].w += a.y * w1.w;
            accv[r].x += a.z * w2.x; accv[r].y += a.z * w2.y; accv[r].z += a.z * w2.z; accv[r].w += a.z * w2.w;
            accv[r].x += a.w * w3.x; accv[r].y += a.w * w3.y; accv[r].z += a.w * w3.z; accv[r].w += a.w * w3.w;
        }
    }

    #pragma unroll
    for (int r = 0; r < RPT; ++r) {
        int rr = row0 + ty * RPT + r;
        if (rr < n) {
            float dv = dinv[rr];
            float4 o = accv[r];
            o.x *= dv; o.y *= dv; o.z *= dv; o.w *= dv;
            ((float4*)y)[(size_t)rr * CG + cg]   = o;
            ((float4*)acc)[(size_t)rr * CG + cg] = o;  // acc starts at y (self loop)
        }
    }
}

// ---------------- edge scatter: acc[col] += y[row] ----------------
// one 64-lane wave per edge

template<int NC>
__global__ __launch_bounds__(256) void scatter_kernel(
    const int* __restrict__ rows, const int* __restrict__ cols, int ne,
    const float* __restrict__ y, float* __restrict__ acc)
{
    int wid  = (int)((blockIdx.x * 256 + threadIdx.x) >> 6);
    int lane = threadIdx.x & 63;
    if (wid >= ne) return;
    int r = rows[wid];
    int c = cols[wid];
    if constexpr (NC == 128) {
        float2 v = ((const float2*)y)[(size_t)r * 64 + lane];
        atomicAdd(&acc[(size_t)c * 128 + lane * 2 + 0], v.x);
        atomicAdd(&acc[(size_t)c * 128 + lane * 2 + 1], v.y);
    } else {
        float v = y[(size_t)r * 64 + lane];
        atomicAdd(&acc[(size_t)c * 64 + lane], v);
    }
}

// ---------------- combine two convs (+bias), optional BN stats ----------------
// out[v] = dinvL[v]*accL[v] + bL + 0.5*(dinvN[v]*accN[v] + bN)

template<int CH, bool STATS>
__global__ __launch_bounds__(256) void combine_kernel(
    const float* __restrict__ accL, const float* __restrict__ accN,
    const float* __restrict__ dinvL, const float* __restrict__ dinvN,
    const float* __restrict__ bL, const float* __restrict__ bN,
    float* __restrict__ out, int n, int rows_per_block,
    float* __restrict__ bn_sum, float* __restrict__ bn_sumsq)
{
    constexpr int RIF = 256 / CH;   // rows in flight
    const int c  = threadIdx.x % CH;
    const int rs = threadIdx.x / CH;
    const int r0 = blockIdx.x * rows_per_block;
    const int rend = min(r0 + rows_per_block, n);

    float s = 0.f, s2 = 0.f;
    const float blv = bL[c], bnv = bN[c];
    for (int r = r0 + rs; r < rend; r += RIF) {
        float v = dinvL[r] * accL[(size_t)r * CH + c] + blv
                + 0.5f * (dinvN[r] * accN[(size_t)r * CH + c] + bnv);
        out[(size_t)r * CH + c] = v;
        if constexpr (STATS) { s += v; s2 += v * v; }
    }
    if constexpr (STATS) {
        __shared__ float ls[256], ls2[256];
        ls[threadIdx.x] = s; ls2[threadIdx.x] = s2;
        __syncthreads();
        if (threadIdx.x < CH) {
            #pragma unroll
            for (int i = 1; i < RIF; ++i) {
                s  += ls[threadIdx.x + i * CH];
                s2 += ls2[threadIdx.x + i * CH];
            }
            atomicAdd(&bn_sum[c], s);
            atomicAdd(&bn_sumsq[c], s2);
        }
    }
}

__global__ void bn_final_kernel(
    const float* __restrict__ sum, const float* __restrict__ sumsq,
    const float* __restrict__ gamma, const float* __restrict__ beta,
    float* __restrict__ scale, float* __restrict__ shift, float inv_n)
{
    int c = threadIdx.x;
    float mean = sum[c] * inv_n;
    float var  = sumsq[c] * inv_n - mean * mean;
    float sc = gamma[c] * rsqrtf(var + 1e-5f);
    scale[c] = sc;
    shift[c] = beta[c] - mean * sc;
}

// ---------------- launch ----------------

extern "C" void kernel_launch(void* const* d_in, const int* in_sizes, int n_in,
                              void* d_out, int out_size, void* d_ws, size_t ws_size,
                              hipStream_t stream)
{
    const float* x     = (const float*)d_in[0];
    const int*   adjL  = (const int*)d_in[1];   // adj_low
    const int*   adjN  = (const int*)d_in[3];   // adj_nd_low (adj_high/nd_high unused)
    const float* W1L   = (const float*)d_in[5];
    const float* b1L   = (const float*)d_in[6];
    const float* W1N   = (const float*)d_in[7];
    const float* b1N   = (const float*)d_in[8];
    const float* gamma = (const float*)d_in[9];
    const float* beta  = (const float*)d_in[10];
    const float* W2L   = (const float*)d_in[11];
    const float* b2L   = (const float*)d_in[12];
    const float* W2N   = (const float*)d_in[13];
    const float* b2N   = (const float*)d_in[14];

    const int n  = in_sizes[0] / 128;
    const int eL = in_sizes[1] / 2;
    const int eN = in_sizes[3] / 2;
    const int* rowL = adjL;  const int* colL = adjL + eL;
    const int* rowN = adjN;  const int* colN = adjN + eN;

    char* p = (char*)d_ws;
    const size_t big = (size_t)n * 128 * sizeof(float);
    float* y1L   = (float*)p; p += big;
    float* y1N   = (float*)p; p += big;
    float* acc1L = (float*)p; p += big;   // later reused as h (pre-BN)
    float* acc1N = (float*)p; p += big;
    float* dinvL = (float*)p; p += (size_t)n * sizeof(float);
    float* dinvN = (float*)p; p += (size_t)n * sizeof(float);
    float* bn_sum   = (float*)p; p += 128 * sizeof(float);
    float* bn_sumsq = (float*)p; p += 128 * sizeof(float);
    float* bn_scale = (float*)p; p += 128 * sizeof(float);
    float* bn_shift = (float*)p; p += 128 * sizeof(float);

    // layer-2 aliases (each [n][64]); y1/acc1 buffers are dead by then
    const size_t half = (size_t)n * 64 * sizeof(float);
    float* y2L   = y1L;
    float* y2N   = (float*)((char*)y1L + half);
    float* acc2L = y1N;
    float* acc2N = (float*)((char*)y1N + half);
    float* h     = acc1L;

    hipMemsetAsync(dinvL, 0, (size_t)n * 2 * sizeof(float), stream);
    hipMemsetAsync(bn_sum, 0, 2 * 128 * sizeof(float), stream);

    {
        int e = eL > eN ? eL : eN;
        count_deg_kernel<<<idiv_up(e, 256), 256, 0, stream>>>(colL, colN, eL, eN, dinvL, dinvN);
        dinv_kernel<<<idiv_up(n, 256), 256, 0, stream>>>(dinvL, dinvN, n);
    }

    // layer 1: xw scaled by dinv, duplicated into gather (y) and scatter-acc buffers
    gemm_kernel<128><<<dim3(idiv_up(n, 64), 2), 256, 0, stream>>>(
        x, n, W1L, W1N, dinvL, dinvN, y1L, y1N, acc1L, acc1N, nullptr, nullptr);

    scatter_kernel<128><<<idiv_up(eL, 4), 256, 0, stream>>>(rowL, colL, eL, y1L, acc1L);
    scatter_kernel<128><<<idiv_up(eN, 4), 256, 0, stream>>>(rowN, colN, eN, y1N, acc1N);

    combine_kernel<128, true><<<idiv_up(n, 128), 256, 0, stream>>>(
        acc1L, acc1N, dinvL, dinvN, b1L, b1N, h, n, 128, bn_sum, bn_sumsq);

    bn_final_kernel<<<1, 128, 0, stream>>>(bn_sum, bn_sumsq, gamma, beta,
                                           bn_scale, bn_shift, 1.0f / (float)n);

    // layer 2: BN+ReLU fused into A-tile load
    gemm_kernel<64><<<dim3(idiv_up(n, 64), 2), 256, 0, stream>>>(
        h, n, W2L, W2N, dinvL, dinvN, y2L, y2N, acc2L, acc2N, bn_scale, bn_shift);

    scatter_kernel<64><<<idiv_up(eL, 4), 256, 0, stream>>>(rowL, colL, eL, y2L, acc2L);
    scatter_kernel<64><<<idiv_up(eN, 4), 256, 0, stream>>>(rowN, colN, eN, y2N, acc2N);

    combine_kernel<64, false><<<idiv_up(n, 128), 256, 0, stream>>>(
        acc2L, acc2N, dinvL, dinvN, b2L, b2N, (float*)d_out, n, 128, nullptr, nullptr);
}

// Round 2
// 1270.258 us; speedup vs baseline: 2.9026x; 2.9026x over previous
//
#include <hip/hip_runtime.h>

static inline int idiv_up(int a, int b) { return (a + b - 1) / b; }

// ---------------- degree histogram (int) ----------------

__global__ __launch_bounds__(256) void count_deg_kernel(
    const int* __restrict__ colL, const int* __restrict__ colN,
    int eL, int eN,
    int* __restrict__ degL, int* __restrict__ degN)
{
    int i = blockIdx.x * 256 + threadIdx.x;
    if (i < eL) atomicAdd(&degL[colL[i]], 1);
    if (i < eN) atomicAdd(&degN[colN[i]], 1);
}

__global__ __launch_bounds__(256) void dinv_kernel(
    const int* __restrict__ degL, const int* __restrict__ degN,
    float* __restrict__ dinvL, float* __restrict__ dinvN, int n)
{
    int i = blockIdx.x * 256 + threadIdx.x;
    if (i < n) {
        dinvL[i] = rsqrtf((float)degL[i] + 1.0f);   // +1 self loop
        dinvN[i] = rsqrtf((float)degN[i] + 1.0f);
    }
}

// ---------------- exclusive scan -> rowptr + cursor (one block per adjacency) ----------------

__global__ __launch_bounds__(1024) void scan_kernel(
    const int* __restrict__ degL, const int* __restrict__ degN, int n,
    int* __restrict__ rowptrL, int* __restrict__ rowptrN,
    int* __restrict__ cursorL, int* __restrict__ cursorN)
{
    const int* deg = blockIdx.x ? degN : degL;
    int* rowptr    = blockIdx.x ? rowptrN : rowptrL;
    int* cursor    = blockIdx.x ? cursorN : cursorL;

    __shared__ int ls[1024];
    const int t = threadIdx.x;
    const int chunk = (n + 1023) / 1024;
    const int base = t * chunk;

    int s = 0;
    for (int i = 0; i < chunk; ++i) {
        int idx = base + i;
        if (idx < n) s += deg[idx];
    }
    ls[t] = s;
    __syncthreads();
    for (int off = 1; off < 1024; off <<= 1) {
        int add = (t >= off) ? ls[t - off] : 0;
        __syncthreads();
        ls[t] += add;
        __syncthreads();
    }
    int running = (t == 0) ? 0 : ls[t - 1];
    int total = ls[1023];
    for (int i = 0; i < chunk; ++i) {
        int idx = base + i;
        if (idx < n) {
            rowptr[idx] = running;
            cursor[idx] = running;
            running += deg[idx];
        }
    }
    if (t == 1023) rowptr[n] = total;
}

// ---------------- CSR placement: csr[pos] = source row ----------------

__global__ __launch_bounds__(256) void place_kernel(
    const int* __restrict__ rowL, const int* __restrict__ colL, int eL,
    const int* __restrict__ rowN, const int* __restrict__ colN, int eN,
    int* __restrict__ curL, int* __restrict__ curN,
    int* __restrict__ csrL, int* __restrict__ csrN)
{
    int i = blockIdx.x * 256 + threadIdx.x;
    if (i < eL) {
        int c = colL[i];
        int p = atomicAdd(&curL[c], 1);
        csrL[p] = rowL[i];
    }
    if (i < eN) {
        int c = colN[i];
        int p = atomicAdd(&curN[c], 1);
        csrN[p] = rowN[i];
    }
}

// ---------------- GEMM: y = (A @ W) * dinv[row] ----------------
// A is [n][128]; optional BN(scale,shift)+ReLU applied to A on load.
// blockIdx.y selects the (W, dinv, y) set: 0 = low, 1 = nd.

template<int NC>
__global__ __launch_bounds__(256) void gemm_kernel(
    const float* __restrict__ A, int n,
    const float* __restrict__ Wa, const float* __restrict__ Wb,
    const float* __restrict__ dinva, const float* __restrict__ dinvb,
    float* __restrict__ ya, float* __restrict__ yb,
    const float* __restrict__ bn_scale, const float* __restrict__ bn_shift)
{
    constexpr int K   = 128;
    constexpr int TR  = 64;        // rows per block
    constexpr int CG  = NC / 4;    // float4 column groups
    constexpr int TY  = 256 / CG;  // thread-row groups
    constexpr int RPT = TR / TY;   // rows per thread

    __shared__ float xs[TR][K];

    const float* W    = blockIdx.y ? Wb    : Wa;
    const float* dinv = blockIdx.y ? dinvb : dinva;
    float* y          = blockIdx.y ? yb    : ya;

    const int row0 = blockIdx.x * TR;
    const int t = threadIdx.x;

    const float4* A4 = (const float4*)A;
    #pragma unroll
    for (int i = 0; i < (TR * (K / 4)) / 256; ++i) {
        int fl = i * 256 + t;
        int r  = fl >> 5;       // K/4 == 32
        int c4 = fl & 31;
        float4 v = make_float4(0.f, 0.f, 0.f, 0.f);
        int rr = row0 + r;
        if (rr < n) v = A4[(size_t)rr * 32 + c4];
        if (bn_scale) {
            float4 sc = ((const float4*)bn_scale)[c4];
            float4 sh = ((const float4*)bn_shift)[c4];
            v.x = fmaxf(v.x * sc.x + sh.x, 0.f);
            v.y = fmaxf(v.y * sc.y + sh.y, 0.f);
            v.z = fmaxf(v.z * sc.z + sh.z, 0.f);
            v.w = fmaxf(v.w * sc.w + sh.w, 0.f);
        }
        *(float4*)&xs[r][c4 * 4] = v;
    }
    __syncthreads();

    const int cg = t % CG;
    const int ty = t / CG;

    float4 accv[RPT];
    #pragma unroll
    for (int r = 0; r < RPT; ++r) accv[r] = make_float4(0.f, 0.f, 0.f, 0.f);

    const float4* W4 = (const float4*)W;
    for (int k = 0; k < K; k += 4) {
        float4 w0 = W4[(size_t)(k + 0) * CG + cg];
        float4 w1 = W4[(size_t)(k + 1) * CG + cg];
        float4 w2 = W4[(size_t)(k + 2) * CG + cg];
        float4 w3 = W4[(size_t)(k + 3) * CG + cg];
        #pragma unroll
        for (int r = 0; r < RPT; ++r) {
            float4 a = *(const float4*)&xs[ty * RPT + r][k];
            accv[r].x += a.x * w0.x; accv[r].y += a.x * w0.y; accv[r].z += a.x * w0.z; accv[r].w += a.x * w0.w;
            accv[r].x += a.y * w1.x; accv[r].y += a.y * w1.y; accv[r].z += a.y * w1.z; accv[r].w += a.y * w1.w;
            accv[r].x += a.z * w2.x; accv[r].y += a.z * w2.y; accv[r].z += a.z * w2.z; accv[r].w += a.z * w2.w;
            accv[r].x += a.w * w3.x; accv[r].y += a.w * w3.y; accv[r].z += a.w * w3.z; accv[r].w += a.w * w3.w;
        }
    }

    #pragma unroll
    for (int r = 0; r < RPT; ++r) {
        int rr = row0 + ty * RPT + r;
        if (rr < n) {
            float dv = dinv[rr];
            float4 o = accv[r];
            o.x *= dv; o.y *= dv; o.z *= dv; o.w *= dv;
            ((float4*)y)[(size_t)rr * CG + cg] = o;
        }
    }
}

// ---------------- fused gather + combine (+bias, BN stats) ----------------
// out[v] = dinvL[v]*(y_L[v] + sum_{u->v} y_L[u]) + bL
//        + 0.5*(dinvN[v]*(y_N[v] + sum y_N[u]) + bN)

template<int CH, bool STATS>
__global__ __launch_bounds__(256) void gather_kernel(
    const int* __restrict__ rowptrL, const int* __restrict__ csrL,
    const int* __restrict__ rowptrN, const int* __restrict__ csrN,
    const float* __restrict__ yL, const float* __restrict__ yN,
    const float* __restrict__ dinvL, const float* __restrict__ dinvN,
    const float* __restrict__ bL, const float* __restrict__ bN,
    float* __restrict__ out, int n,
    float* __restrict__ bn_sum, float* __restrict__ bn_sumsq)
{
    constexpr int NPB = 256 / CH;       // nodes per block-iteration
    const int c  = threadIdx.x % CH;
    const int ns = threadIdx.x / CH;
    const float blv = bL[c], bnv = bN[c];

    float s = 0.f, s2 = 0.f;

    for (int node0 = blockIdx.x * NPB; node0 < n; node0 += gridDim.x * NPB) {
        const int node = node0 + ns;
        if (node < n) {
            float sL = yL[(size_t)node * CH + c];
            {
                int j = rowptrL[node], end = rowptrL[node + 1];
                for (; j + 4 <= end; j += 4) {
                    int u0 = csrL[j], u1 = csrL[j+1], u2 = csrL[j+2], u3 = csrL[j+3];
                    sL += yL[(size_t)u0 * CH + c] + yL[(size_t)u1 * CH + c]
                        + yL[(size_t)u2 * CH + c] + yL[(size_t)u3 * CH + c];
                }
                for (; j < end; ++j) sL += yL[(size_t)csrL[j] * CH + c];
            }
            float sN = yN[(size_t)node * CH + c];
            {
                int j = rowptrN[node], end = rowptrN[node + 1];
                for (; j + 4 <= end; j += 4) {
                    int u0 = csrN[j], u1 = csrN[j+1], u2 = csrN[j+2], u3 = csrN[j+3];
                    sN += yN[(size_t)u0 * CH + c] + yN[(size_t)u1 * CH + c]
                        + yN[(size_t)u2 * CH + c] + yN[(size_t)u3 * CH + c];
                }
                for (; j < end; ++j) sN += yN[(size_t)csrN[j] * CH + c];
            }
            float v = dinvL[node] * sL + blv + 0.5f * (dinvN[node] * sN + bnv);
            out[(size_t)node * CH + c] = v;
            if constexpr (STATS) { s += v; s2 += v * v; }
        }
    }

    if constexpr (STATS) {
        __shared__ float ls[256], ls2[256];
        ls[threadIdx.x] = s; ls2[threadIdx.x] = s2;
        __syncthreads();
        if (threadIdx.x < CH) {
            float ss = 0.f, ss2 = 0.f;
            #pragma unroll
            for (int i = 0; i < NPB; ++i) {
                ss  += ls[threadIdx.x + i * CH];
                ss2 += ls2[threadIdx.x + i * CH];
            }
            atomicAdd(&bn_sum[threadIdx.x], ss);
            atomicAdd(&bn_sumsq[threadIdx.x], ss2);
        }
    }
}

__global__ void bn_final_kernel(
    const float* __restrict__ sum, const float* __restrict__ sumsq,
    const float* __restrict__ gamma, const float* __restrict__ beta,
    float* __restrict__ scale, float* __restrict__ shift, float inv_n)
{
    int c = threadIdx.x;
    float mean = sum[c] * inv_n;
    float var  = sumsq[c] * inv_n - mean * mean;
    float sc = gamma[c] * rsqrtf(var + 1e-5f);
    scale[c] = sc;
    shift[c] = beta[c] - mean * sc;
}

// ---------------- launch ----------------

extern "C" void kernel_launch(void* const* d_in, const int* in_sizes, int n_in,
                              void* d_out, int out_size, void* d_ws, size_t ws_size,
                              hipStream_t stream)
{
    const float* x     = (const float*)d_in[0];
    const int*   adjL  = (const int*)d_in[1];   // adj_low
    const int*   adjN  = (const int*)d_in[3];   // adj_nd_low (adj_high/nd_high unused)
    const float* W1L   = (const float*)d_in[5];
    const float* b1L   = (const float*)d_in[6];
    const float* W1N   = (const float*)d_in[7];
    const float* b1N   = (const float*)d_in[8];
    const float* gamma = (const float*)d_in[9];
    const float* beta  = (const float*)d_in[10];
    const float* W2L   = (const float*)d_in[11];
    const float* b2L   = (const float*)d_in[12];
    const float* W2N   = (const float*)d_in[13];
    const float* b2N   = (const float*)d_in[14];

    const int n  = in_sizes[0] / 128;
    const int eL = in_sizes[1] / 2;
    const int eN = in_sizes[3] / 2;
    const int* rowL = adjL;  const int* colL = adjL + eL;
    const int* rowN = adjN;  const int* colN = adjN + eN;

    char* p = (char*)d_ws;
    const size_t big = (size_t)n * 128 * sizeof(float);
    float* y1L = (float*)p; p += big;
    float* y1N = (float*)p; p += big;
    float* h   = (float*)p; p += big;        // pre-BN layer-1 output
    float* dinvL = (float*)p; p += (size_t)n * sizeof(float);
    float* dinvN = (float*)p; p += (size_t)n * sizeof(float);
    float* bn_sum   = (float*)p; p += 128 * sizeof(float);
    float* bn_sumsq = (float*)p; p += 128 * sizeof(float);
    float* bn_scale = (float*)p; p += 128 * sizeof(float);
    float* bn_shift = (float*)p; p += 128 * sizeof(float);
    int* degL    = (int*)p; p += (size_t)n * sizeof(int);
    int* degN    = (int*)p; p += (size_t)n * sizeof(int);
    int* rowptrL = (int*)p; p += (size_t)(n + 1) * sizeof(int);
    int* rowptrN = (int*)p; p += (size_t)(n + 1) * sizeof(int);
    int* cursorL = (int*)p; p += (size_t)n * sizeof(int);
    int* cursorN = (int*)p; p += (size_t)n * sizeof(int);
    int* csrL    = (int*)p; p += (size_t)eL * sizeof(int);
    int* csrN    = (int*)p; p += (size_t)eN * sizeof(int);

    // layer-2 gather sources reuse y1L space ([n][64] each)
    float* y2L = y1L;
    float* y2N = y1L + (size_t)n * 64;

    hipMemsetAsync(degL, 0, (size_t)n * 2 * sizeof(int), stream);
    hipMemsetAsync(bn_sum, 0, 2 * 128 * sizeof(float), stream);

    const int emax = eL > eN ? eL : eN;
    count_deg_kernel<<<idiv_up(emax, 256), 256, 0, stream>>>(colL, colN, eL, eN, degL, degN);
    dinv_kernel<<<idiv_up(n, 256), 256, 0, stream>>>(degL, degN, dinvL, dinvN, n);
    scan_kernel<<<2, 1024, 0, stream>>>(degL, degN, n, rowptrL, rowptrN, cursorL, cursorN);
    place_kernel<<<idiv_up(emax, 256), 256, 0, stream>>>(
        rowL, colL, eL, rowN, colN, eN, cursorL, cursorN, csrL, csrN);

    // layer 1
    gemm_kernel<128><<<dim3(idiv_up(n, 64), 2), 256, 0, stream>>>(
        x, n, W1L, W1N, dinvL, dinvN, y1L, y1N, nullptr, nullptr);

    gather_kernel<128, true><<<4096, 256, 0, stream>>>(
        rowptrL, csrL, rowptrN, csrN, y1L, y1N, dinvL, dinvN,
        b1L, b1N, h, n, bn_sum, bn_sumsq);

    bn_final_kernel<<<1, 128, 0, stream>>>(bn_sum, bn_sumsq, gamma, beta,
                                           bn_scale, bn_shift, 1.0f / (float)n);

    // layer 2 (BN+ReLU fused into GEMM A-load)
    gemm_kernel<64><<<dim3(idiv_up(n, 64), 2), 256, 0, stream>>>(
        h, n, W2L, W2N, dinvL, dinvN, y2L, y2N, bn_scale, bn_shift);

    gather_kernel<64, false><<<4096, 256, 0, stream>>>(
        rowptrL, csrL, rowptrN, csrN, y2L, y2N, dinvL, dinvN,
        b2L, b2N, (float*)d_out, n, nullptr, nullptr);
}

// Round 3
// 1152.214 us; speedup vs baseline: 3.1999x; 1.1024x over previous
//
#include <hip/hip_runtime.h>

typedef unsigned int u32;

static inline int idiv_up(int a, int b) { return (a + b - 1) / b; }

// ---------------- bf16 pack/unpack ----------------

__device__ __forceinline__ u32 pack_bf16_rne(float lo, float hi) {
    u32 ul = __float_as_uint(lo);
    u32 uh = __float_as_uint(hi);
    ul = (ul + 0x7fffu + ((ul >> 16) & 1u)) >> 16;
    uh = (uh + 0x7fffu + ((uh >> 16) & 1u));
    return (ul & 0xffffu) | (uh & 0xffff0000u);
}
__device__ __forceinline__ float bf16_lo(u32 u) { return __uint_as_float(u << 16); }
__device__ __forceinline__ float bf16_hi(u32 u) { return __uint_as_float(u & 0xffff0000u); }

// ---------------- degree histogram (int) ----------------

__global__ __launch_bounds__(256) void count_deg_kernel(
    const int* __restrict__ colL, const int* __restrict__ colN,
    int eL, int eN,
    int* __restrict__ degL, int* __restrict__ degN)
{
    int i = blockIdx.x * 256 + threadIdx.x;
    if (i < eL) atomicAdd(&degL[colL[i]], 1);
    if (i < eN) atomicAdd(&degN[colN[i]], 1);
}

__global__ __launch_bounds__(256) void dinv_kernel(
    const int* __restrict__ degL, const int* __restrict__ degN,
    float* __restrict__ dinvL, float* __restrict__ dinvN, int n)
{
    int i = blockIdx.x * 256 + threadIdx.x;
    if (i < n) {
        dinvL[i] = rsqrtf((float)degL[i] + 1.0f);   // +1 self loop
        dinvN[i] = rsqrtf((float)degN[i] + 1.0f);
    }
}

// ---------------- exclusive scan -> rowptr + cursor ----------------

__global__ __launch_bounds__(1024) void scan_kernel(
    const int* __restrict__ degL, const int* __restrict__ degN, int n,
    int* __restrict__ rowptrL, int* __restrict__ rowptrN,
    int* __restrict__ cursorL, int* __restrict__ cursorN)
{
    const int* deg = blockIdx.x ? degN : degL;
    int* rowptr    = blockIdx.x ? rowptrN : rowptrL;
    int* cursor    = blockIdx.x ? cursorN : cursorL;

    __shared__ int ls[1024];
    const int t = threadIdx.x;
    const int chunk = (n + 1023) / 1024;
    const int base = t * chunk;

    int s = 0;
    for (int i = 0; i < chunk; ++i) {
        int idx = base + i;
        if (idx < n) s += deg[idx];
    }
    ls[t] = s;
    __syncthreads();
    for (int off = 1; off < 1024; off <<= 1) {
        int add = (t >= off) ? ls[t - off] : 0;
        __syncthreads();
        ls[t] += add;
        __syncthreads();
    }
    int running = (t == 0) ? 0 : ls[t - 1];
    int total = ls[1023];
    for (int i = 0; i < chunk; ++i) {
        int idx = base + i;
        if (idx < n) {
            rowptr[idx] = running;
            cursor[idx] = running;
            running += deg[idx];
        }
    }
    if (t == 1023) rowptr[n] = total;
}

// ---------------- CSR placement ----------------

__global__ __launch_bounds__(256) void place_kernel(
    const int* __restrict__ rowL, const int* __restrict__ colL, int eL,
    const int* __restrict__ rowN, const int* __restrict__ colN, int eN,
    int* __restrict__ curL, int* __restrict__ curN,
    int* __restrict__ csrL, int* __restrict__ csrN)
{
    int i = blockIdx.x * 256 + threadIdx.x;
    if (i < eL) {
        int c = colL[i];
        int p = atomicAdd(&curL[c], 1);
        csrL[p] = rowL[i];
    }
    if (i < eN) {
        int c = colN[i];
        int p = atomicAdd(&curN[c], 1);
        csrN[p] = rowN[i];
    }
}

// ---------------- GEMM: y(bf16) = (A @ W) * dinv[row] ----------------
// A is [n][128] fp32; optional BN(scale,shift)+ReLU applied to A on load.
// y stored as [n][NC] bf16 (u32 pairs). blockIdx.y: 0 = low, 1 = nd.

template<int NC>
__global__ __launch_bounds__(256) void gemm_kernel(
    const float* __restrict__ A, int n,
    const float* __restrict__ Wa, const float* __restrict__ Wb,
    const float* __restrict__ dinva, const float* __restrict__ dinvb,
    u32* __restrict__ ya, u32* __restrict__ yb,
    const float* __restrict__ bn_scale, const float* __restrict__ bn_shift)
{
    constexpr int K   = 128;
    constexpr int TR  = 64;        // rows per block
    constexpr int CG  = NC / 4;    // float4 column groups
    constexpr int TY  = 256 / CG;  // thread-row groups
    constexpr int RPT = TR / TY;   // rows per thread

    __shared__ float xs[TR][K];

    const float* W    = blockIdx.y ? Wb    : Wa;
    const float* dinv = blockIdx.y ? dinvb : dinva;
    u32* y            = blockIdx.y ? yb    : ya;

    const int row0 = blockIdx.x * TR;
    const int t = threadIdx.x;

    const float4* A4 = (const float4*)A;
    #pragma unroll
    for (int i = 0; i < (TR * (K / 4)) / 256; ++i) {
        int fl = i * 256 + t;
        int r  = fl >> 5;       // K/4 == 32
        int c4 = fl & 31;
        float4 v = make_float4(0.f, 0.f, 0.f, 0.f);
        int rr = row0 + r;
        if (rr < n) v = A4[(size_t)rr * 32 + c4];
        if (bn_scale) {
            float4 sc = ((const float4*)bn_scale)[c4];
            float4 sh = ((const float4*)bn_shift)[c4];
            v.x = fmaxf(v.x * sc.x + sh.x, 0.f);
            v.y = fmaxf(v.y * sc.y + sh.y, 0.f);
            v.z = fmaxf(v.z * sc.z + sh.z, 0.f);
            v.w = fmaxf(v.w * sc.w + sh.w, 0.f);
        }
        *(float4*)&xs[r][c4 * 4] = v;
    }
    __syncthreads();

    const int cg = t % CG;
    const int ty = t / CG;

    float4 accv[RPT];
    #pragma unroll
    for (int r = 0; r < RPT; ++r) accv[r] = make_float4(0.f, 0.f, 0.f, 0.f);

    const float4* W4 = (const float4*)W;
    for (int k = 0; k < K; k += 4) {
        float4 w0 = W4[(size_t)(k + 0) * CG + cg];
        float4 w1 = W4[(size_t)(k + 1) * CG + cg];
        float4 w2 = W4[(size_t)(k + 2) * CG + cg];
        float4 w3 = W4[(size_t)(k + 3) * CG + cg];
        #pragma unroll
        for (int r = 0; r < RPT; ++r) {
            float4 a = *(const float4*)&xs[ty * RPT + r][k];
            accv[r].x += a.x * w0.x; accv[r].y += a.x * w0.y; accv[r].z += a.x * w0.z; accv[r].w += a.x * w0.w;
            accv[r].x += a.y * w1.x; accv[r].y += a.y * w1.y; accv[r].z += a.y * w1.z; accv[r].w += a.y * w1.w;
            accv[r].x += a.z * w2.x; accv[r].y += a.z * w2.y; accv[r].z += a.z * w2.z; accv[r].w += a.z * w2.w;
            accv[r].x += a.w * w3.x; accv[r].y += a.w * w3.y; accv[r].z += a.w * w3.z; accv[r].w += a.w * w3.w;
        }
    }

    #pragma unroll
    for (int r = 0; r < RPT; ++r) {
        int rr = row0 + ty * RPT + r;
        if (rr < n) {
            float dv = dinv[rr];
            float4 o = accv[r];
            o.x *= dv; o.y *= dv; o.z *= dv; o.w *= dv;
            uint2 pk;
            pk.x = pack_bf16_rne(o.x, o.y);
            pk.y = pack_bf16_rne(o.z, o.w);
            ((uint2*)y)[(size_t)rr * CG + cg] = pk;
        }
    }
}

// ---------------- fused gather + combine (+bias, BN stats) ----------------
// out[v] = dinvL[v]*(y_L[v] + sum_{u->v} y_L[u]) + bL
//        + 0.5*(dinvN[v]*(y_N[v] + sum y_N[u]) + bN)
// y tables are bf16; each thread owns 2 adjacent channels (one u32).

template<int CH, bool STATS>
__global__ __launch_bounds__(256) void gather_kernel(
    const int* __restrict__ rowptrL, const int* __restrict__ csrL,
    const int* __restrict__ rowptrN, const int* __restrict__ csrN,
    const u32* __restrict__ yL, const u32* __restrict__ yN,
    const float* __restrict__ dinvL, const float* __restrict__ dinvN,
    const float* __restrict__ bL, const float* __restrict__ bN,
    float* __restrict__ out, int n,
    float* __restrict__ bn_sum, float* __restrict__ bn_sumsq)
{
    constexpr int CHW = CH / 2;         // u32 lanes per node
    constexpr int NPB = 256 / CHW;      // nodes per block-iteration
    const int c  = threadIdx.x % CHW;
    const int ns = threadIdx.x / CHW;
    const float2 blv = ((const float2*)bL)[c];
    const float2 bnv = ((const float2*)bN)[c];

    float s0 = 0.f, s1 = 0.f, q0 = 0.f, q1 = 0.f;

    for (int node0 = blockIdx.x * NPB; node0 < n; node0 += gridDim.x * NPB) {
        const int node = node0 + ns;
        if (node < n) {
            u32 uself = yL[(size_t)node * CHW + c];
            float sL0 = bf16_lo(uself), sL1 = bf16_hi(uself);
            {
                int j = rowptrL[node], end = rowptrL[node + 1];
                for (; j + 4 <= end; j += 4) {
                    int u0 = csrL[j], u1 = csrL[j+1], u2 = csrL[j+2], u3 = csrL[j+3];
                    u32 a0 = yL[(size_t)u0 * CHW + c];
                    u32 a1 = yL[(size_t)u1 * CHW + c];
                    u32 a2 = yL[(size_t)u2 * CHW + c];
                    u32 a3 = yL[(size_t)u3 * CHW + c];
                    sL0 += bf16_lo(a0) + bf16_lo(a1) + bf16_lo(a2) + bf16_lo(a3);
                    sL1 += bf16_hi(a0) + bf16_hi(a1) + bf16_hi(a2) + bf16_hi(a3);
                }
                for (; j < end; ++j) {
                    u32 a = yL[(size_t)csrL[j] * CHW + c];
                    sL0 += bf16_lo(a); sL1 += bf16_hi(a);
                }
            }
            u32 vself = yN[(size_t)node * CHW + c];
            float sN0 = bf16_lo(vself), sN1 = bf16_hi(vself);
            {
                int j = rowptrN[node], end = rowptrN[node + 1];
                for (; j + 4 <= end; j += 4) {
                    int u0 = csrN[j], u1 = csrN[j+1], u2 = csrN[j+2], u3 = csrN[j+3];
                    u32 a0 = yN[(size_t)u0 * CHW + c];
                    u32 a1 = yN[(size_t)u1 * CHW + c];
                    u32 a2 = yN[(size_t)u2 * CHW + c];
                    u32 a3 = yN[(size_t)u3 * CHW + c];
                    sN0 += bf16_lo(a0) + bf16_lo(a1) + bf16_lo(a2) + bf16_lo(a3);
                    sN1 += bf16_hi(a0) + bf16_hi(a1) + bf16_hi(a2) + bf16_hi(a3);
                }
                for (; j < end; ++j) {
                    u32 a = yN[(size_t)csrN[j] * CHW + c];
                    sN0 += bf16_lo(a); sN1 += bf16_hi(a);
                }
            }
            float dl = dinvL[node], dn = dinvN[node];
            float v0 = dl * sL0 + blv.x + 0.5f * (dn * sN0 + bnv.x);
            float v1 = dl * sL1 + blv.y + 0.5f * (dn * sN1 + bnv.y);
            ((float2*)out)[(size_t)node * CHW + c] = make_float2(v0, v1);
            if constexpr (STATS) { s0 += v0; s1 += v1; q0 += v0 * v0; q1 += v1 * v1; }
        }
    }

    if constexpr (STATS) {
        __shared__ float4 ls[256];
        ls[threadIdx.x] = make_float4(s0, s1, q0, q1);
        __syncthreads();
        if (threadIdx.x < CHW) {
            float4 a = ls[threadIdx.x];
            #pragma unroll
            for (int i = 1; i < NPB; ++i) {
                float4 b = ls[threadIdx.x + i * CHW];
                a.x += b.x; a.y += b.y; a.z += b.z; a.w += b.w;
            }
            atomicAdd(&bn_sum[2 * threadIdx.x + 0], a.x);
            atomicAdd(&bn_sum[2 * threadIdx.x + 1], a.y);
            atomicAdd(&bn_sumsq[2 * threadIdx.x + 0], a.z);
            atomicAdd(&bn_sumsq[2 * threadIdx.x + 1], a.w);
        }
    }
}

__global__ void bn_final_kernel(
    const float* __restrict__ sum, const float* __restrict__ sumsq,
    const float* __restrict__ gamma, const float* __restrict__ beta,
    float* __restrict__ scale, float* __restrict__ shift, float inv_n)
{
    int c = threadIdx.x;
    float mean = sum[c] * inv_n;
    float var  = sumsq[c] * inv_n - mean * mean;
    float sc = gamma[c] * rsqrtf(var + 1e-5f);
    scale[c] = sc;
    shift[c] = beta[c] - mean * sc;
}

// ---------------- launch ----------------

extern "C" void kernel_launch(void* const* d_in, const int* in_sizes, int n_in,
                              void* d_out, int out_size, void* d_ws, size_t ws_size,
                              hipStream_t stream)
{
    const float* x     = (const float*)d_in[0];
    const int*   adjL  = (const int*)d_in[1];   // adj_low
    const int*   adjN  = (const int*)d_in[3];   // adj_nd_low (adj_high/nd_high unused)
    const float* W1L   = (const float*)d_in[5];
    const float* b1L   = (const float*)d_in[6];
    const float* W1N   = (const float*)d_in[7];
    const float* b1N   = (const float*)d_in[8];
    const float* gamma = (const float*)d_in[9];
    const float* beta  = (const float*)d_in[10];
    const float* W2L   = (const float*)d_in[11];
    const float* b2L   = (const float*)d_in[12];
    const float* W2N   = (const float*)d_in[13];
    const float* b2N   = (const float*)d_in[14];

    const int n  = in_sizes[0] / 128;
    const int eL = in_sizes[1] / 2;
    const int eN = in_sizes[3] / 2;
    const int* rowL = adjL;  const int* colL = adjL + eL;
    const int* rowN = adjN;  const int* colN = adjN + eN;

    char* p = (char*)d_ws;
    const size_t ybytes = (size_t)n * 128 * sizeof(short);   // bf16 [n][128]
    u32* y1L = (u32*)p; p += ybytes;
    u32* y1N = (u32*)p; p += ybytes;
    float* h = (float*)p; p += (size_t)n * 128 * sizeof(float);
    float* dinvL = (float*)p; p += (size_t)n * sizeof(float);
    float* dinvN = (float*)p; p += (size_t)n * sizeof(float);
    float* bn_sum   = (float*)p; p += 128 * sizeof(float);
    float* bn_sumsq = (float*)p; p += 128 * sizeof(float);
    float* bn_scale = (float*)p; p += 128 * sizeof(float);
    float* bn_shift = (float*)p; p += 128 * sizeof(float);
    int* degL    = (int*)p; p += (size_t)n * sizeof(int);
    int* degN    = (int*)p; p += (size_t)n * sizeof(int);
    int* rowptrL = (int*)p; p += (size_t)(n + 1) * sizeof(int);
    int* rowptrN = (int*)p; p += (size_t)(n + 1) * sizeof(int);
    int* cursorL = (int*)p; p += (size_t)n * sizeof(int);
    int* cursorN = (int*)p; p += (size_t)n * sizeof(int);
    int* csrL    = (int*)p; p += (size_t)eL * sizeof(int);
    int* csrN    = (int*)p; p += (size_t)eN * sizeof(int);

    // layer-2 y tables ([n][64] bf16 each) reuse y1L space (exactly fits)
    u32* y2L = y1L;
    u32* y2N = y1L + (size_t)n * 32;

    hipMemsetAsync(degL, 0, (size_t)n * 2 * sizeof(int), stream);
    hipMemsetAsync(bn_sum, 0, 2 * 128 * sizeof(float), stream);

    const int emax = eL > eN ? eL : eN;
    count_deg_kernel<<<idiv_up(emax, 256), 256, 0, stream>>>(colL, colN, eL, eN, degL, degN);
    dinv_kernel<<<idiv_up(n, 256), 256, 0, stream>>>(degL, degN, dinvL, dinvN, n);
    scan_kernel<<<2, 1024, 0, stream>>>(degL, degN, n, rowptrL, rowptrN, cursorL, cursorN);
    place_kernel<<<idiv_up(emax, 256), 256, 0, stream>>>(
        rowL, colL, eL, rowN, colN, eN, cursorL, cursorN, csrL, csrN);

    // layer 1
    gemm_kernel<128><<<dim3(idiv_up(n, 64), 2), 256, 0, stream>>>(
        x, n, W1L, W1N, dinvL, dinvN, y1L, y1N, nullptr, nullptr);

    gather_kernel<128, true><<<4096, 256, 0, stream>>>(
        rowptrL, csrL, rowptrN, csrN, y1L, y1N, dinvL, dinvN,
        b1L, b1N, h, n, bn_sum, bn_sumsq);

    bn_final_kernel<<<1, 128, 0, stream>>>(bn_sum, bn_sumsq, gamma, beta,
                                           bn_scale, bn_shift, 1.0f / (float)n);

    // layer 2 (BN+ReLU fused into GEMM A-load)
    gemm_kernel<64><<<dim3(idiv_up(n, 64), 2), 256, 0, stream>>>(
        h, n, W2L, W2N, dinvL, dinvN, y2L, y2N, bn_scale, bn_shift);

    gather_kernel<64, false><<<4096, 256, 0, stream>>>(
        rowptrL, csrL, rowptrN, csrN, y2L, y2N, dinvL, dinvN,
        b2L, b2N, (float*)d_out, n, nullptr, nullptr);
}